// Round 1
// baseline (8421.941 us; speedup 1.0000x reference)
//
#include <hip/hip_runtime.h>

// LSTM: B=64, S=512, D=H=O=1024.
// Plan:
//  1) convert x -> bf16, transposed to [s][b][d] (GEMM row = m = s*64+b)
//  2) pack Wx,Wh -> bf16 rows n' = k*4 + gate (gate-interleaved so the step
//     kernel's 64-col tile holds all 4 gates for 16 k values)
//  3) xg = x @ Wx^T  (big bf16 MFMA GEMM, 32768x4096x1024), stored bf16
//  4) 512 sequential step kernels: g = h@Wh^T + xg_t + (bx+bh); fused
//     sigmoid/tanh/c-update epilogue; h saved per-step (bf16) for y-GEMM
//  5) y = h_all @ Wp^T + bp  (32768x1024x1024), scattered to out[b][s][o]
//  6) tail: final (c,h) f32 -> out
// Workspace: ~422 MB.

typedef unsigned short u16;
typedef u16   u16x4  __attribute__((ext_vector_type(4)));
typedef u16   u16x8  __attribute__((ext_vector_type(8)));
typedef __bf16 bf16x8 __attribute__((ext_vector_type(8)));
typedef float f32x4  __attribute__((ext_vector_type(4)));

__device__ __forceinline__ u16 f2bf(float x) {
    unsigned u = __float_as_uint(x);
    u = (u + 0x7FFFu + ((u >> 16) & 1u)) >> 16;   // RNE
    return (u16)u;
}
__device__ __forceinline__ float bf2f(u16 h) {
    return __uint_as_float(((unsigned)h) << 16);
}
__device__ __forceinline__ float fsig(float x) { return 1.f / (1.f + __expf(-x)); }
__device__ __forceinline__ float ftanh(float x) { return 1.f - 2.f / (__expf(2.f * x) + 1.f); }

// ---- conversion / packing kernels -----------------------------------------

// x[b][s][d] f32 -> xb[(s*64+b)][d] bf16.  grid = B*S blocks, 256 thr.
__global__ void k_convert_x(const float* __restrict__ x, u16* __restrict__ xb) {
    int bi = blockIdx.x;            // = b*512 + s  (x row order)
    int b = bi >> 9, s = bi & 511;
    const float4* src = (const float4*)(x + (size_t)bi * 1024);
    u16* dst = xb + ((size_t)(s * 64 + b)) * 1024;
    int t = threadIdx.x;
    float4 v = src[t];
    u16x4 o; o.x = f2bf(v.x); o.y = f2bf(v.y); o.z = f2bf(v.z); o.w = f2bf(v.w);
    *(u16x4*)(dst + t * 4) = o;
}

// W[4][1024][1024] f32 -> wp[n'=k*4+g][1024] bf16.  grid = 4096 blocks.
__global__ void k_pack_gates(const float* __restrict__ w, u16* __restrict__ wp) {
    int np = blockIdx.x;
    int g = np & 3, k = np >> 2;
    const float4* src = (const float4*)(w + ((size_t)(g * 1024 + k)) * 1024);
    u16* dst = wp + (size_t)np * 1024;
    int t = threadIdx.x;
    float4 v = src[t];
    u16x4 o; o.x = f2bf(v.x); o.y = f2bf(v.y); o.z = f2bf(v.z); o.w = f2bf(v.w);
    *(u16x4*)(dst + t * 4) = o;
}

// plain f32 -> bf16 copy (Wp). n must be multiple of 1024.
__global__ void k_f2bf(const float* __restrict__ src, u16* __restrict__ dst, int n) {
    int i = (blockIdx.x * 256 + threadIdx.x) * 4;
    if (i < n) {
        float4 v = *(const float4*)(src + i);
        u16x4 o; o.x = f2bf(v.x); o.y = f2bf(v.y); o.z = f2bf(v.z); o.w = f2bf(v.w);
        *(u16x4*)(dst + i) = o;
    }
}

// bias[n'] = bx[g][k] + bh[g][k], n' = k*4+g. 4096 elems.
__global__ void k_bias(const float* __restrict__ bx, const float* __restrict__ bh,
                       float* __restrict__ bias) {
    int np = blockIdx.x * 256 + threadIdx.x;
    int g = np & 3, k = np >> 2;
    bias[np] = bx[g * 1024 + k] + bh[g * 1024 + k];
}

// zero h[slot 0] and c state. 65536 elems each.
__global__ void k_init(u16* __restrict__ hall0, float* __restrict__ cstate) {
    int i = blockIdx.x * 256 + threadIdx.x;
    hall0[i] = 0;
    cstate[i] = 0.f;
}

// ---- generic 64x64-tile bf16 GEMM (C = A @ Bt^T) --------------------------
// A: [M][K] bf16 row-major. Bt: [N][K] bf16 row-major.
// mode 0: Cb[m*N + n] = bf16(acc)                      (xg precompute)
// mode 1: Cf[(b*S_ + s)*O_ + n] = acc + bp[n], m=s*64+b (output projection)
__global__ __launch_bounds__(256) void k_gemm64(
    const u16* __restrict__ A, const u16* __restrict__ Bt,
    int K, int N, int mode,
    u16* __restrict__ Cb,
    float* __restrict__ Cf, const float* __restrict__ bp, int S_, int O_) {
    __shared__ u16 As[64 * 72];   // +8 pad: 2-way max bank aliasing (free)
    __shared__ u16 Bs[64 * 72];
    int mb = blockIdx.x, nb = blockIdx.y;
    int tid = threadIdx.x, w = tid >> 6, lane = tid & 63;
    f32x4 acc[4] = {};
    int kchunks = K >> 6;
    for (int kc = 0; kc < kchunks; ++kc) {
        int k0 = kc * 64;
#pragma unroll
        for (int r = 0; r < 2; ++r) {
            int c = tid + 256 * r;            // 0..511: 16B chunks
            int row = c >> 3, kk = (c & 7) * 8;
            *(u16x8*)(&As[row * 72 + kk]) =
                *(const u16x8*)(A + (size_t)(mb * 64 + row) * K + k0 + kk);
            *(u16x8*)(&Bs[row * 72 + kk]) =
                *(const u16x8*)(Bt + (size_t)(nb * 64 + row) * K + k0 + kk);
        }
        __syncthreads();
#pragma unroll
        for (int kk = 0; kk < 64; kk += 32) {
            bf16x8 a = *(const bf16x8*)(&As[(w * 16 + (lane & 15)) * 72 + kk + (lane >> 4) * 8]);
#pragma unroll
            for (int nt = 0; nt < 4; ++nt) {
                bf16x8 b = *(const bf16x8*)(&Bs[(nt * 16 + (lane & 15)) * 72 + kk + (lane >> 4) * 8]);
                acc[nt] = __builtin_amdgcn_mfma_f32_16x16x32_bf16(a, b, acc[nt], 0, 0, 0);
            }
        }
        __syncthreads();
    }
    int q = lane >> 4, cl = lane & 15;
    if (mode == 0) {
#pragma unroll
        for (int nt = 0; nt < 4; ++nt)
#pragma unroll
            for (int j = 0; j < 4; ++j) {
                int m = mb * 64 + w * 16 + q * 4 + j;
                int n = nb * 64 + nt * 16 + cl;
                Cb[(size_t)m * N + n] = f2bf(acc[nt][j]);
            }
    } else {
#pragma unroll
        for (int nt = 0; nt < 4; ++nt)
#pragma unroll
            for (int j = 0; j < 4; ++j) {
                int m = mb * 64 + w * 16 + q * 4 + j;
                int n = nb * 64 + nt * 16 + cl;
                int b = m & 63, s = m >> 6;
                Cf[((size_t)b * S_ + s) * O_ + n] = acc[nt][j] + bp[n];
            }
    }
}

// ---- one LSTM step: g = h@Wh^T + xg_t + bias; fused gate epilogue ---------
// grid = 64 blocks (each owns all 64 b-rows x 64 n'-cols = 16 k values).
__global__ __launch_bounds__(256) void k_step(
    const u16* __restrict__ hprev,   // hall + t*65536   [64][1024] bf16
    const u16* __restrict__ whp,     // [4096][1024] bf16, gate-interleaved
    const u16* __restrict__ xgt,     // xg + t*64*4096   [64][4096] bf16
    const float* __restrict__ bias,  // [4096]
    float* __restrict__ cstate,      // [64][1024] f32 (in/out)
    float* __restrict__ hf32,        // [64][1024] f32 (out, last step = final h)
    u16* __restrict__ hnext) {       // hall + (t+1)*65536
    __shared__ u16 As[64 * 72];
    __shared__ u16 Bs[64 * 72];
    __shared__ float glds[64 * 72];
    int nb = blockIdx.x;
    int tid = threadIdx.x, w = tid >> 6, lane = tid & 63;
    f32x4 acc[4] = {};
    for (int kc = 0; kc < 16; ++kc) {
        int k0 = kc * 64;
#pragma unroll
        for (int r = 0; r < 2; ++r) {
            int c = tid + 256 * r;
            int row = c >> 3, kk = (c & 7) * 8;
            *(u16x8*)(&As[row * 72 + kk]) =
                *(const u16x8*)(hprev + (size_t)row * 1024 + k0 + kk);
            *(u16x8*)(&Bs[row * 72 + kk]) =
                *(const u16x8*)(whp + (size_t)(nb * 64 + row) * 1024 + k0 + kk);
        }
        __syncthreads();
#pragma unroll
        for (int kk = 0; kk < 64; kk += 32) {
            bf16x8 a = *(const bf16x8*)(&As[(w * 16 + (lane & 15)) * 72 + kk + (lane >> 4) * 8]);
#pragma unroll
            for (int nt = 0; nt < 4; ++nt) {
                bf16x8 b = *(const bf16x8*)(&Bs[(nt * 16 + (lane & 15)) * 72 + kk + (lane >> 4) * 8]);
                acc[nt] = __builtin_amdgcn_mfma_f32_16x16x32_bf16(a, b, acc[nt], 0, 0, 0);
            }
        }
        __syncthreads();
    }
    // write g = acc + xg + bias into LDS (full 64x64 tile for this block)
    int q = lane >> 4, cl = lane & 15;
#pragma unroll
    for (int nt = 0; nt < 4; ++nt)
#pragma unroll
        for (int j = 0; j < 4; ++j) {
            int brow = w * 16 + q * 4 + j;
            int ncl = nt * 16 + cl;
            int n = nb * 64 + ncl;
            glds[brow * 72 + ncl] = acc[nt][j] + bf2f(xgt[(size_t)brow * 4096 + n]) + bias[n];
        }
    __syncthreads();
    // gate math: 64 b x 16 k items; cols 4k..4k+3 are gates i,f,o,c
#pragma unroll
    for (int r = 0; r < 4; ++r) {
        int id = tid + 256 * r;          // 0..1023
        int b = id >> 4, kl = id & 15;
        float4 gv = *(const float4*)(&glds[b * 72 + kl * 4]);
        float ig = fsig(gv.x), fg = fsig(gv.y), og = fsig(gv.z), cc = ftanh(gv.w);
        int k = nb * 16 + kl;
        float c_old = cstate[b * 1024 + k];
        float c_new = fg * c_old + ig * cc;
        cstate[b * 1024 + k] = c_new;
        float h = og * ftanh(c_new);
        hf32[b * 1024 + k] = h;
        hnext[b * 1024 + k] = f2bf(h);
    }
}

// final (c,h) -> d_out tail. 131072 elems.
__global__ void k_tail(const float* __restrict__ cstate, const float* __restrict__ hf32,
                       float* __restrict__ out) {
    int i = blockIdx.x * 256 + threadIdx.x;
    if (i < 65536) out[33554432 + i] = cstate[i];
    else           out[33554432 + i] = hf32[i - 65536];
}

extern "C" void kernel_launch(void* const* d_in, const int* in_sizes, int n_in,
                              void* d_out, int out_size, void* d_ws, size_t ws_size,
                              hipStream_t stream) {
    const float* x  = (const float*)d_in[0];
    const float* Wx = (const float*)d_in[1];
    const float* bx = (const float*)d_in[2];
    const float* Wh = (const float*)d_in[3];
    const float* bh = (const float*)d_in[4];
    const float* Wp = (const float*)d_in[5];
    const float* bp = (const float*)d_in[6];
    float* out = (float*)d_out;
    char* ws = (char*)d_ws;

    // workspace layout (bytes), total ~422 MB
    u16*   xb   = (u16*)  (ws);                   // 64 MB  [32768][1024] bf16
    u16*   wxp  = (u16*)  (ws + 67108864);        // 8 MB   [4096][1024]
    u16*   whp  = (u16*)  (ws + 75497472);        // 8 MB   [4096][1024]
    u16*   wpb  = (u16*)  (ws + 83886080);        // 2 MB   [1024][1024]
    float* bias = (float*)(ws + 85983232);        // 16 KB  [4096]
    float* cst  = (float*)(ws + 85999616);        // 256 KB [64][1024]
    float* hf32 = (float*)(ws + 86261760);        // 256 KB [64][1024]
    u16*   xg   = (u16*)  (ws + 86523904);        // 256 MB [32768][4096]
    u16*   hall = (u16*)  (ws + 354959360);       // 64.1 MB [513][64][1024]

    k_convert_x<<<32768, 256, 0, stream>>>(x, xb);
    k_pack_gates<<<4096, 256, 0, stream>>>(Wx, wxp);
    k_pack_gates<<<4096, 256, 0, stream>>>(Wh, whp);
    k_f2bf<<<1024, 256, 0, stream>>>(Wp, wpb, 1048576);
    k_bias<<<16, 256, 0, stream>>>(bx, bh, bias);
    k_init<<<256, 256, 0, stream>>>(hall, cst);

    // xg = x @ Wx^T : M=32768, N=4096, K=1024
    k_gemm64<<<dim3(512, 64), 256, 0, stream>>>(xb, wxp, 1024, 4096, 0,
                                                xg, nullptr, nullptr, 0, 0);
    // sequential recurrence
    for (int t = 0; t < 512; ++t) {
        k_step<<<64, 256, 0, stream>>>(hall + (size_t)t * 65536, whp,
                                       xg + (size_t)t * 64 * 4096, bias,
                                       cst, hf32, hall + (size_t)(t + 1) * 65536);
    }
    // y = h_all @ Wp^T : M=32768, N=1024, K=1024; scatter to out[b][s][o]
    k_gemm64<<<dim3(512, 16), 256, 0, stream>>>(hall + 65536, wpb, 1024, 1024, 1,
                                                nullptr, out, bp, 512, 1024);
    k_tail<<<512, 256, 0, stream>>>(cst, hf32, out);
}

// Round 2
// 4962.673 us; speedup vs baseline: 1.6971x; 1.6971x over previous
//
#include <hip/hip_runtime.h>

// LSTM: B=64, S=512, D=H=O=1024.
// R2 change: step kernel retiled 64 blocks -> 256 blocks (16 gate-interleaved
// cols x 64 rows x K=1024 each, BK=256). Recurrence was launch/latency bound
// at 64 blocks (1/4 of CUs used).
//
// Plan:
//  1) convert x -> bf16, transposed to [s][b][d] (GEMM row = m = s*64+b)
//  2) pack Wx,Wh -> bf16 rows n' = k*4 + gate (gate-interleaved so a step
//     block's 16-col tile holds all 4 gates for 4 k values)
//  3) xg = x @ Wx^T  (big bf16 MFMA GEMM, 32768x4096x1024), stored bf16
//  4) 512 sequential step kernels: g = h@Wh^T + xg_t + (bx+bh); fused
//     sigmoid/tanh/c-update epilogue; h saved per-step (bf16) for y-GEMM
//  5) y = h_all @ Wp^T + bp  (32768x1024x1024), scattered to out[b][s][o]
//  6) tail: final (c,h) f32 -> out

typedef unsigned short u16;
typedef u16   u16x4  __attribute__((ext_vector_type(4)));
typedef u16   u16x8  __attribute__((ext_vector_type(8)));
typedef __bf16 bf16x8 __attribute__((ext_vector_type(8)));
typedef float f32x4  __attribute__((ext_vector_type(4)));

__device__ __forceinline__ u16 f2bf(float x) {
    unsigned u = __float_as_uint(x);
    u = (u + 0x7FFFu + ((u >> 16) & 1u)) >> 16;   // RNE
    return (u16)u;
}
__device__ __forceinline__ float bf2f(u16 h) {
    return __uint_as_float(((unsigned)h) << 16);
}
__device__ __forceinline__ float fsig(float x) { return 1.f / (1.f + __expf(-x)); }
__device__ __forceinline__ float ftanh(float x) { return 1.f - 2.f / (__expf(2.f * x) + 1.f); }

// ---- conversion / packing kernels -----------------------------------------

// x[b][s][d] f32 -> xb[(s*64+b)][d] bf16.  grid = B*S blocks, 256 thr.
__global__ void k_convert_x(const float* __restrict__ x, u16* __restrict__ xb) {
    int bi = blockIdx.x;            // = b*512 + s  (x row order)
    int b = bi >> 9, s = bi & 511;
    const float4* src = (const float4*)(x + (size_t)bi * 1024);
    u16* dst = xb + ((size_t)(s * 64 + b)) * 1024;
    int t = threadIdx.x;
    float4 v = src[t];
    u16x4 o; o.x = f2bf(v.x); o.y = f2bf(v.y); o.z = f2bf(v.z); o.w = f2bf(v.w);
    *(u16x4*)(dst + t * 4) = o;
}

// W[4][1024][1024] f32 -> wp[n'=k*4+g][1024] bf16.  grid = 4096 blocks.
__global__ void k_pack_gates(const float* __restrict__ w, u16* __restrict__ wp) {
    int np = blockIdx.x;
    int g = np & 3, k = np >> 2;
    const float4* src = (const float4*)(w + ((size_t)(g * 1024 + k)) * 1024);
    u16* dst = wp + (size_t)np * 1024;
    int t = threadIdx.x;
    float4 v = src[t];
    u16x4 o; o.x = f2bf(v.x); o.y = f2bf(v.y); o.z = f2bf(v.z); o.w = f2bf(v.w);
    *(u16x4*)(dst + t * 4) = o;
}

// plain f32 -> bf16 copy (Wp). n must be multiple of 1024.
__global__ void k_f2bf(const float* __restrict__ src, u16* __restrict__ dst, int n) {
    int i = (blockIdx.x * 256 + threadIdx.x) * 4;
    if (i < n) {
        float4 v = *(const float4*)(src + i);
        u16x4 o; o.x = f2bf(v.x); o.y = f2bf(v.y); o.z = f2bf(v.z); o.w = f2bf(v.w);
        *(u16x4*)(dst + i) = o;
    }
}

// bias[n'] = bx[g][k] + bh[g][k], n' = k*4+g. 4096 elems.
__global__ void k_bias(const float* __restrict__ bx, const float* __restrict__ bh,
                       float* __restrict__ bias) {
    int np = blockIdx.x * 256 + threadIdx.x;
    int g = np & 3, k = np >> 2;
    bias[np] = bx[g * 1024 + k] + bh[g * 1024 + k];
}

// zero h[slot 0] and c state. 65536 elems each.
__global__ void k_init(u16* __restrict__ hall0, float* __restrict__ cstate) {
    int i = blockIdx.x * 256 + threadIdx.x;
    hall0[i] = 0;
    cstate[i] = 0.f;
}

// ---- generic 64x64-tile bf16 GEMM (C = A @ Bt^T) --------------------------
// A: [M][K] bf16 row-major. Bt: [N][K] bf16 row-major.
// mode 0: Cb[m*N + n] = bf16(acc)                      (xg precompute)
// mode 1: Cf[(b*S_ + s)*O_ + n] = acc + bp[n], m=s*64+b (output projection)
__global__ __launch_bounds__(256) void k_gemm64(
    const u16* __restrict__ A, const u16* __restrict__ Bt,
    int K, int N, int mode,
    u16* __restrict__ Cb,
    float* __restrict__ Cf, const float* __restrict__ bp, int S_, int O_) {
    __shared__ u16 As[64 * 72];   // +8 pad
    __shared__ u16 Bs[64 * 72];
    int mb = blockIdx.x, nb = blockIdx.y;
    int tid = threadIdx.x, w = tid >> 6, lane = tid & 63;
    f32x4 acc[4] = {};
    int kchunks = K >> 6;
    for (int kc = 0; kc < kchunks; ++kc) {
        int k0 = kc * 64;
#pragma unroll
        for (int r = 0; r < 2; ++r) {
            int c = tid + 256 * r;            // 0..511: 16B chunks
            int row = c >> 3, kk = (c & 7) * 8;
            *(u16x8*)(&As[row * 72 + kk]) =
                *(const u16x8*)(A + (size_t)(mb * 64 + row) * K + k0 + kk);
            *(u16x8*)(&Bs[row * 72 + kk]) =
                *(const u16x8*)(Bt + (size_t)(nb * 64 + row) * K + k0 + kk);
        }
        __syncthreads();
#pragma unroll
        for (int kk = 0; kk < 64; kk += 32) {
            bf16x8 a = *(const bf16x8*)(&As[(w * 16 + (lane & 15)) * 72 + kk + (lane >> 4) * 8]);
#pragma unroll
            for (int nt = 0; nt < 4; ++nt) {
                bf16x8 b = *(const bf16x8*)(&Bs[(nt * 16 + (lane & 15)) * 72 + kk + (lane >> 4) * 8]);
                acc[nt] = __builtin_amdgcn_mfma_f32_16x16x32_bf16(a, b, acc[nt], 0, 0, 0);
            }
        }
        __syncthreads();
    }
    int q = lane >> 4, cl = lane & 15;
    if (mode == 0) {
#pragma unroll
        for (int nt = 0; nt < 4; ++nt)
#pragma unroll
            for (int j = 0; j < 4; ++j) {
                int m = mb * 64 + w * 16 + q * 4 + j;
                int n = nb * 64 + nt * 16 + cl;
                Cb[(size_t)m * N + n] = f2bf(acc[nt][j]);
            }
    } else {
#pragma unroll
        for (int nt = 0; nt < 4; ++nt)
#pragma unroll
            for (int j = 0; j < 4; ++j) {
                int m = mb * 64 + w * 16 + q * 4 + j;
                int n = nb * 64 + nt * 16 + cl;
                int b = m & 63, s = m >> 6;
                Cf[((size_t)b * S_ + s) * O_ + n] = acc[nt][j] + bp[n];
            }
    }
}

// ---- one LSTM step, 256-block version -------------------------------------
// Block nb owns cols n = nb*16 .. nb*16+15 (= k-values nb*4..nb*4+3, all 4
// gates), all 64 m-rows, full K=1024 in BK=256 chunks. Wave w computes the
// 16x16 tile for m-rows w*16..w*16+15. Fused gate epilogue per block.
__global__ __launch_bounds__(256) void k_step(
    const u16* __restrict__ hprev,   // [64][1024] bf16
    const u16* __restrict__ whp,     // [4096][1024] bf16, gate-interleaved
    const u16* __restrict__ xgt,     // [64][4096] bf16
    const float* __restrict__ bias,  // [4096]
    float* __restrict__ cstate,      // [64][1024] f32 (in/out)
    float* __restrict__ hf32,        // [64][1024] f32 (out)
    u16* __restrict__ hnext) {       // [64][1024] bf16
    __shared__ u16 As[64 * 264];     // 64 x (256+8), 33792 B
    __shared__ u16 Bs[16 * 264];     // 8448 B
    __shared__ float glds[64 * 20];  // 5120 B
    int nb = blockIdx.x;             // 0..255
    int tid = threadIdx.x, w = tid >> 6, lane = tid & 63;
    f32x4 acc = {};
    for (int kc = 0; kc < 4; ++kc) {
        int k0 = kc * 256;
        // stage A (h): 64 rows x 256 cols = 2048 x 16B chunks, 8 per thread
#pragma unroll
        for (int r = 0; r < 8; ++r) {
            int c = tid + 256 * r;            // 0..2047
            int row = c >> 5, kk = (c & 31) * 8;
            *(u16x8*)(&As[row * 264 + kk]) =
                *(const u16x8*)(hprev + (size_t)row * 1024 + k0 + kk);
        }
        // stage B (Wh rows): 16 rows x 256 cols = 512 chunks, 2 per thread
#pragma unroll
        for (int r = 0; r < 2; ++r) {
            int c = tid + 256 * r;            // 0..511
            int row = c >> 5, kk = (c & 31) * 8;
            *(u16x8*)(&Bs[row * 264 + kk]) =
                *(const u16x8*)(whp + (size_t)(nb * 16 + row) * 1024 + k0 + kk);
        }
        __syncthreads();
#pragma unroll
        for (int kk = 0; kk < 256; kk += 32) {
            bf16x8 a = *(const bf16x8*)(&As[(w * 16 + (lane & 15)) * 264 + kk + (lane >> 4) * 8]);
            bf16x8 b = *(const bf16x8*)(&Bs[(lane & 15) * 264 + kk + (lane >> 4) * 8]);
            acc = __builtin_amdgcn_mfma_f32_16x16x32_bf16(a, b, acc, 0, 0, 0);
        }
        __syncthreads();
    }
    // g = acc + xg + bias -> LDS tile [64 rows][16 cols]
    int q = lane >> 4, cl = lane & 15;
#pragma unroll
    for (int j = 0; j < 4; ++j) {
        int row = w * 16 + q * 4 + j;
        int n = nb * 16 + cl;
        glds[row * 20 + cl] = acc[j] + bf2f(xgt[(size_t)row * 4096 + n]) + bias[n];
    }
    __syncthreads();
    // gate math: 256 items = 64 rows x 4 k-values, one per thread
    {
        int row = tid >> 2, kv = tid & 3;
        float4 gv = *(const float4*)(&glds[row * 20 + kv * 4]);
        float ig = fsig(gv.x), fg = fsig(gv.y), og = fsig(gv.z), cc = ftanh(gv.w);
        int k = nb * 4 + kv;
        float c_old = cstate[row * 1024 + k];
        float c_new = fg * c_old + ig * cc;
        cstate[row * 1024 + k] = c_new;
        float h = og * ftanh(c_new);
        hf32[row * 1024 + k] = h;
        hnext[row * 1024 + k] = f2bf(h);
    }
}

// final (c,h) -> d_out tail. 131072 elems.
__global__ void k_tail(const float* __restrict__ cstate, const float* __restrict__ hf32,
                       float* __restrict__ out) {
    int i = blockIdx.x * 256 + threadIdx.x;
    if (i < 65536) out[33554432 + i] = cstate[i];
    else           out[33554432 + i] = hf32[i - 65536];
}

extern "C" void kernel_launch(void* const* d_in, const int* in_sizes, int n_in,
                              void* d_out, int out_size, void* d_ws, size_t ws_size,
                              hipStream_t stream) {
    const float* x  = (const float*)d_in[0];
    const float* Wx = (const float*)d_in[1];
    const float* bx = (const float*)d_in[2];
    const float* Wh = (const float*)d_in[3];
    const float* bh = (const float*)d_in[4];
    const float* Wp = (const float*)d_in[5];
    const float* bp = (const float*)d_in[6];
    float* out = (float*)d_out;
    char* ws = (char*)d_ws;

    // workspace layout (bytes), total ~422 MB
    u16*   xb   = (u16*)  (ws);                   // 64 MB  [32768][1024] bf16
    u16*   wxp  = (u16*)  (ws + 67108864);        // 8 MB   [4096][1024]
    u16*   whp  = (u16*)  (ws + 75497472);        // 8 MB   [4096][1024]
    u16*   wpb  = (u16*)  (ws + 83886080);        // 2 MB   [1024][1024]
    float* bias = (float*)(ws + 85983232);        // 16 KB  [4096]
    float* cst  = (float*)(ws + 85999616);        // 256 KB [64][1024]
    float* hf32 = (float*)(ws + 86261760);        // 256 KB [64][1024]
    u16*   xg   = (u16*)  (ws + 86523904);        // 256 MB [32768][4096]
    u16*   hall = (u16*)  (ws + 354959360);       // 64.1 MB [513][64][1024]

    k_convert_x<<<32768, 256, 0, stream>>>(x, xb);
    k_pack_gates<<<4096, 256, 0, stream>>>(Wx, wxp);
    k_pack_gates<<<4096, 256, 0, stream>>>(Wh, whp);
    k_f2bf<<<1024, 256, 0, stream>>>(Wp, wpb, 1048576);
    k_bias<<<16, 256, 0, stream>>>(bx, bh, bias);
    k_init<<<256, 256, 0, stream>>>(hall, cst);

    // xg = x @ Wx^T : M=32768, N=4096, K=1024
    k_gemm64<<<dim3(512, 64), 256, 0, stream>>>(xb, wxp, 1024, 4096, 0,
                                                xg, nullptr, nullptr, 0, 0);
    // sequential recurrence, 256 blocks per step
    for (int t = 0; t < 512; ++t) {
        k_step<<<256, 256, 0, stream>>>(hall + (size_t)t * 65536, whp,
                                        xg + (size_t)t * 64 * 4096, bias,
                                        cst, hf32, hall + (size_t)(t + 1) * 65536);
    }
    // y = h_all @ Wp^T : M=32768, N=1024, K=1024; scatter to out[b][s][o]
    k_gemm64<<<dim3(512, 16), 256, 0, stream>>>(hall + 65536, wpb, 1024, 1024, 1,
                                                nullptr, out, bp, 512, 1024);
    k_tail<<<512, 256, 0, stream>>>(cst, hf32, out);
}